// Round 4
// baseline (385.139 us; speedup 1.0000x reference)
//
#include <hip/hip_runtime.h>
#include <hip/hip_bf16.h>

#define SEQ 2048
#define HD 128
#define NH 32
#define NKV 8
#define ODIM 4096
#define QB 64
#define KVB 64
#define SCALE 0.08838834764831845f
#define NEGBIG -1e9f

typedef __attribute__((ext_vector_type(8))) short bf16x8;
typedef __attribute__((ext_vector_type(4))) float f32x4;

__device__ __forceinline__ unsigned short f2bf(float x) {
  union { float f; unsigned u; } c; c.f = x;
  unsigned r = c.u + 0x7FFFu + ((c.u >> 16) & 1u);
  return (unsigned short)(r >> 16);
}

__global__ __launch_bounds__(256) void sdpa_flash_kernel(
    const float* __restrict__ q, const float* __restrict__ k,
    const float* __restrict__ v, float* __restrict__ out) {
  // LDS: K tile [64][128] bf16 (16KB) + V^T tile [128][64] bf16 (16KB)
  //      + per-wave P buffer [16][64] bf16 (4 x 2KB)
  __shared__ __align__(16) unsigned char smem[40960];
  unsigned char* Klds = smem;
  unsigned char* Vlds = smem + 16384;
  const int tid = threadIdx.x;
  const int w = tid >> 6;
  const int l = tid & 63;
  const int lm = l & 15;
  const int lg = l >> 4;
  unsigned char* Plds = smem + 32768 + (w << 11);

  const int qt = (int)gridDim.x - 1 - (int)blockIdx.x;  // heavy blocks first
  const int h = (int)blockIdx.y;
  const int hkv = h >> 2;  // repeat_interleave: kv head = h / 4
  const int q0 = qt * QB;
  const int qbase = q0 + 16 * w;

  // ---- Q fragments, pre-scaled by 1/sqrt(D) ----
  // A-frag: lane holds Q[q = lm][d = 32*c + 8*lg + j], j=0..7 contiguous
  bf16x8 qa[4];
  {
    const float* qr = q + ((size_t)(h * SEQ + qbase + lm)) * HD + 8 * lg;
    #pragma unroll
    for (int c = 0; c < 4; ++c) {
      float4 a = *(const float4*)(qr + 32 * c);
      float4 b = *(const float4*)(qr + 32 * c + 4);
      union { unsigned short hh[8]; bf16x8 vv; } pk;
      pk.hh[0] = f2bf(a.x * SCALE); pk.hh[1] = f2bf(a.y * SCALE);
      pk.hh[2] = f2bf(a.z * SCALE); pk.hh[3] = f2bf(a.w * SCALE);
      pk.hh[4] = f2bf(b.x * SCALE); pk.hh[5] = f2bf(b.y * SCALE);
      pk.hh[6] = f2bf(b.z * SCALE); pk.hh[7] = f2bf(b.w * SCALE);
      qa[c] = pk.vv;
    }
  }

  f32x4 o[8];
  #pragma unroll
  for (int i = 0; i < 8; ++i) o[i] = (f32x4){0.f, 0.f, 0.f, 0.f};
  float mrow[4] = {-1e30f, -1e30f, -1e30f, -1e30f};
  float lrow[4] = {0.f, 0.f, 0.f, 0.f};

  const int ntiles = qt + 1;
  const float* kg0 = k + (size_t)hkv * SEQ * HD;
  const float* vg0 = v + (size_t)hkv * SEQ * HD;

  for (int t = 0; t < ntiles; ++t) {
    const int kv0 = t * KVB;
    __syncthreads();  // previous tile's LDS reads complete

    // ---- stage K tile: natural [kv][d], f32->bf16, XOR-swizzled rows ----
    {
      const float* kg = kg0 + (size_t)kv0 * HD;
      #pragma unroll
      for (int it = 0; it < 4; ++it) {
        int idx = it * 256 + tid;
        int r = idx >> 4;           // kv row 0..63
        int c8 = (idx & 15) << 3;   // d start
        const float* src = kg + r * HD + c8;
        float4 a = *(const float4*)(src);
        float4 b = *(const float4*)(src + 4);
        union { unsigned short hh[8]; uint4 u4; } pk;
        pk.hh[0]=f2bf(a.x); pk.hh[1]=f2bf(a.y); pk.hh[2]=f2bf(a.z); pk.hh[3]=f2bf(a.w);
        pk.hh[4]=f2bf(b.x); pk.hh[5]=f2bf(b.y); pk.hh[6]=f2bf(b.z); pk.hh[7]=f2bf(b.w);
        int byte = (r << 8) + ((c8 << 1) ^ ((r & 7) << 4));
        *(uint4*)(Klds + byte) = pk.u4;
      }
      // ---- stage V transposed: [d][kv], scalar bf16 writes, swizzled ----
      const float* vg = vg0 + (size_t)kv0 * HD;
      #pragma unroll
      for (int it = 0; it < 4; ++it) {
        int idx = it * 256 + tid;
        int r = idx >> 4;
        int c8 = (idx & 15) << 3;
        const float* src = vg + r * HD + c8;
        float4 a = *(const float4*)(src);
        float4 b = *(const float4*)(src + 4);
        float vals[8] = {a.x, a.y, a.z, a.w, b.x, b.y, b.z, b.w};
        #pragma unroll
        for (int j = 0; j < 8; ++j) {
          int d = c8 + j;
          int byte = (d << 7) + ((r << 1) ^ ((d & 7) << 4));
          *(unsigned short*)(Vlds + byte) = f2bf(vals[j]);
        }
      }
    }
    __syncthreads();

    // ---- S = Q K^T  (D-layout: row q = 4*lg+i, col kv = 16*nt+lm) ----
    f32x4 s[4];
    #pragma unroll
    for (int nt = 0; nt < 4; ++nt) s[nt] = (f32x4){0.f, 0.f, 0.f, 0.f};
    #pragma unroll
    for (int nt = 0; nt < 4; ++nt) {
      int r = (nt << 4) + lm;
      #pragma unroll
      for (int kc = 0; kc < 4; ++kc) {
        int byte = (r << 8) + (((kc << 6) + (lg << 4)) ^ ((r & 7) << 4));
        bf16x8 kb = *(const bf16x8*)(Klds + byte);
        s[nt] = __builtin_amdgcn_mfma_f32_16x16x32_bf16(qa[kc], kb, s[nt], 0, 0, 0);
      }
    }

    // ---- causal mask (additive -1e9 like the reference) ----
    if (kv0 + KVB - 1 > qbase) {
      #pragma unroll
      for (int nt = 0; nt < 4; ++nt) {
        int col = kv0 + (nt << 4) + lm;
        #pragma unroll
        for (int i = 0; i < 4; ++i) {
          int row = qbase + (lg << 2) + i;
          s[nt][i] += (col > row) ? NEGBIG : 0.f;
        }
      }
    }

    // ---- online softmax: per-lane 4 rows, 16-lane group reduce ----
    float tmax[4];
    #pragma unroll
    for (int i = 0; i < 4; ++i)
      tmax[i] = fmaxf(fmaxf(s[0][i], s[1][i]), fmaxf(s[2][i], s[3][i]));
    #pragma unroll
    for (int d = 1; d < 16; d <<= 1) {
      #pragma unroll
      for (int i = 0; i < 4; ++i)
        tmax[i] = fmaxf(tmax[i], __shfl_xor(tmax[i], d));
    }
    float fac[4];
    #pragma unroll
    for (int i = 0; i < 4; ++i) {
      float mn = fmaxf(mrow[i], tmax[i]);
      fac[i] = __expf(mrow[i] - mn);
      mrow[i] = mn;
    }
    float rsum[4] = {0.f, 0.f, 0.f, 0.f};
    #pragma unroll
    for (int nt = 0; nt < 4; ++nt) {
      #pragma unroll
      for (int i = 0; i < 4; ++i) {
        float p = __expf(s[nt][i] - mrow[i]);
        s[nt][i] = p;
        rsum[i] += p;
      }
    }
    #pragma unroll
    for (int d = 1; d < 16; d <<= 1) {
      #pragma unroll
      for (int i = 0; i < 4; ++i) rsum[i] += __shfl_xor(rsum[i], d);
    }
    #pragma unroll
    for (int i = 0; i < 4; ++i) lrow[i] = lrow[i] * fac[i] + rsum[i];
    #pragma unroll
    for (int nt2 = 0; nt2 < 8; ++nt2) {
      #pragma unroll
      for (int i = 0; i < 4; ++i) o[nt2][i] *= fac[i];
    }

    // ---- P: D-layout -> A-layout via per-wave swizzled LDS transpose ----
    #pragma unroll
    for (int nt = 0; nt < 4; ++nt) {
      int colb = ((nt << 4) + lm) << 1;
      #pragma unroll
      for (int i = 0; i < 4; ++i) {
        int row = (lg << 2) + i;
        *(unsigned short*)(Plds + (row << 7) + (colb ^ ((row & 7) << 4))) =
            f2bf(s[nt][i]);
      }
    }
    asm volatile("s_waitcnt lgkmcnt(0)" ::: "memory");
    bf16x8 pa[2];
    #pragma unroll
    for (int kc = 0; kc < 2; ++kc) {
      int byte = (lm << 7) + (((kc << 6) + (lg << 4)) ^ ((lm & 7) << 4));
      pa[kc] = *(const bf16x8*)(Plds + byte);
    }

    // ---- O += P V  (V^T in LDS gives contiguous-k B-frags) ----
    #pragma unroll
    for (int nt2 = 0; nt2 < 8; ++nt2) {
      int dr = (nt2 << 4) + lm;
      #pragma unroll
      for (int kc = 0; kc < 2; ++kc) {
        int byte = (dr << 7) + (((kc << 6) + (lg << 4)) ^ ((dr & 7) << 4));
        bf16x8 vb = *(const bf16x8*)(Vlds + byte);
        o[nt2] = __builtin_amdgcn_mfma_f32_16x16x32_bf16(pa[kc], vb, o[nt2], 0, 0, 0);
      }
    }
  }

  // ---- epilogue: O /= l, store f32 ----
  float inv[4];
  #pragma unroll
  for (int i = 0; i < 4; ++i) inv[i] = 1.f / lrow[i];
  #pragma unroll
  for (int nt2 = 0; nt2 < 8; ++nt2) {
    int col = h * HD + (nt2 << 4) + lm;
    #pragma unroll
    for (int i = 0; i < 4; ++i) {
      int row = qbase + (lg << 2) + i;
      out[(size_t)row * ODIM + col] = o[nt2][i] * inv[i];
    }
  }
}

extern "C" void kernel_launch(void* const* d_in, const int* in_sizes, int n_in,
                              void* d_out, int out_size, void* d_ws, size_t ws_size,
                              hipStream_t stream) {
  // inputs: [0]=input_pos(i64) [1]=q(f32) [2]=k(f32) [3]=v(f32)
  //         [4]=bsz [5]=seqlen [6]=mask(f32, pure causal -> computed analytically)
  const float* q = (const float*)d_in[1];
  const float* k = (const float*)d_in[2];
  const float* v = (const float*)d_in[3];
  float* out = (float*)d_out;
  dim3 grid(SEQ / QB, NH);
  sdpa_flash_kernel<<<grid, 256, 0, stream>>>(q, k, v, out);
}

// Round 6
// 182.582 us; speedup vs baseline: 2.1094x; 2.1094x over previous
//
#include <hip/hip_runtime.h>
#include <hip/hip_bf16.h>

#define SEQ 2048
#define HD 128
#define NH 32
#define NKV 8
#define ODIM 4096
#define QB 64
#define KVB 64
#define SCALE 0.08838834764831845f
#define NEGBIG -1e9f

typedef __attribute__((ext_vector_type(8))) short bf16x8;
typedef __attribute__((ext_vector_type(4))) float f32x4;

__device__ __forceinline__ unsigned short f2bf(float x) {
  union { __hip_bfloat16 b; unsigned short u; } c;
  c.b = __float2bfloat16(x);  // RNE, single HW cvt
  return c.u;
}

__device__ __forceinline__ unsigned pack2bf(float lo, float hi) {
  union { __hip_bfloat162 h; unsigned u; } c;
  c.h = __float22bfloat162_rn(float2{lo, hi});  // x=lo (low 16b), y=hi
  return c.u;
}

// Block p handles Q-tiles {p, 31-p}: balanced 33 compute-units per block.
// 8 waves: w<4 -> tile A (qt=p) strip w; w>=4 -> tile B (qt=31-p) strip w-4.
__global__ __launch_bounds__(512, 4) void sdpa_flash_kernel(
    const float* __restrict__ q, const float* __restrict__ k,
    const float* __restrict__ v, float* __restrict__ out) {
  // LDS: K [64][128] bf16 swz (16KB) + V^T [128][64] bf16 swz (16KB)
  //      + per-wave P buffer [16][64] bf16 (8 x 2KB)
  __shared__ __align__(16) unsigned char smem[49152];
  unsigned char* Klds = smem;
  unsigned char* Vlds = smem + 16384;
  const int tid = threadIdx.x;
  const int w = tid >> 6;
  const int l = tid & 63;
  const int lm = l & 15;
  const int lg = l >> 4;
  unsigned char* Plds = smem + 32768 + (w << 11);

  const int p = (int)blockIdx.x;       // 0..15
  const int qtA = p;
  const int qtB = 31 - p;
  const int myqt = (w < 4) ? qtA : qtB;
  const int h = (int)blockIdx.y;
  const int hkv = h >> 2;              // repeat_interleave: kv head = h / 4
  const int qbase = myqt * QB + 16 * (w & 3);

  // ---- Q fragments, pre-scaled by 1/sqrt(D) ----
  // A-frag: lane holds Q[q = lm][d = 32*c + 8*lg + j], j=0..7 contiguous
  bf16x8 qa[4];
  {
    const float* qr = q + ((size_t)(h * SEQ + qbase + lm)) * HD + 8 * lg;
    #pragma unroll
    for (int c = 0; c < 4; ++c) {
      float4 a = *(const float4*)(qr + 32 * c);
      float4 b = *(const float4*)(qr + 32 * c + 4);
      union { unsigned short hh[8]; bf16x8 vv; } pk;
      pk.hh[0] = f2bf(a.x * SCALE); pk.hh[1] = f2bf(a.y * SCALE);
      pk.hh[2] = f2bf(a.z * SCALE); pk.hh[3] = f2bf(a.w * SCALE);
      pk.hh[4] = f2bf(b.x * SCALE); pk.hh[5] = f2bf(b.y * SCALE);
      pk.hh[6] = f2bf(b.z * SCALE); pk.hh[7] = f2bf(b.w * SCALE);
      qa[c] = pk.vv;
    }
  }

  f32x4 o[8];
  #pragma unroll
  for (int i = 0; i < 8; ++i) o[i] = (f32x4){0.f, 0.f, 0.f, 0.f};
  float mrow[4] = {-1e30f, -1e30f, -1e30f, -1e30f};
  float lrow[4] = {0.f, 0.f, 0.f, 0.f};

  const int ntiles = qtB + 1;  // union of both halves' needs
  const float* kg0 = k + (size_t)hkv * SEQ * HD;
  const float* vg0 = v + (size_t)hkv * SEQ * HD;

  for (int t = 0; t < ntiles; ++t) {
    const int kv0 = t * KVB;
    __syncthreads();  // previous tile's LDS reads complete

    // ---- stage K tile: [kv][d] bf16, b128 writes, XOR-swizzled ----
    {
      const float* kg = kg0 + (size_t)kv0 * HD;
      #pragma unroll
      for (int it = 0; it < 2; ++it) {
        int idx = it * 512 + tid;   // 0..1023
        int r = idx >> 4;           // kv row 0..63
        int c8 = (idx & 15) << 3;   // d start
        const float* src = kg + r * HD + c8;
        float4 a = *(const float4*)(src);
        float4 b = *(const float4*)(src + 4);
        union { unsigned short hh[8]; uint4 u4; } pk;
        pk.hh[0]=f2bf(a.x); pk.hh[1]=f2bf(a.y); pk.hh[2]=f2bf(a.z); pk.hh[3]=f2bf(a.w);
        pk.hh[4]=f2bf(b.x); pk.hh[5]=f2bf(b.y); pk.hh[6]=f2bf(b.z); pk.hh[7]=f2bf(b.w);
        int byte = (r << 8) + ((c8 << 1) ^ ((r & 7) << 4));
        *(uint4*)(Klds + byte) = pk.u4;
      }
      // ---- stage V^T: [d][kv] bf16, packed kv-pair b32 writes ----
      // bank = (lane&31)^(4j): all 32 banks, 2 lanes/bank -> conflict-free
      const float* vg = vg0 + (size_t)kv0 * HD;
      {
        int idx = tid;               // 0..511, one pass
        int rr = (idx & 31) << 1;    // even kv row
        int db = idx >> 5;           // d-block 0..15
        const float* s0 = vg + rr * HD + (db << 3);
        const float* s1 = s0 + HD;
        float4 a0 = *(const float4*)(s0);
        float4 b0 = *(const float4*)(s0 + 4);
        float4 a1 = *(const float4*)(s1);
        float4 b1 = *(const float4*)(s1 + 4);
        float lo[8] = {a0.x,a0.y,a0.z,a0.w,b0.x,b0.y,b0.z,b0.w};
        float hi[8] = {a1.x,a1.y,a1.z,a1.w,b1.x,b1.y,b1.z,b1.w};
        #pragma unroll
        for (int j = 0; j < 8; ++j) {
          int d = (db << 3) + j;
          int byte = (d << 7) + ((rr << 1) ^ ((d & 7) << 4));
          *(unsigned*)(Vlds + byte) = pack2bf(lo[j], hi[j]);
        }
      }
    }
    __syncthreads();

    if (t <= myqt) {  // wave-uniform guard; A-waves idle past their diagonal
      // ---- S = Q K^T  (D-layout: row q = 4*lg+i, col kv = 16*nt+lm) ----
      f32x4 s[4];
      #pragma unroll
      for (int nt = 0; nt < 4; ++nt) s[nt] = (f32x4){0.f, 0.f, 0.f, 0.f};
      #pragma unroll
      for (int nt = 0; nt < 4; ++nt) {
        int r = (nt << 4) + lm;
        #pragma unroll
        for (int kc = 0; kc < 4; ++kc) {
          int byte = (r << 8) + (((kc << 6) + (lg << 4)) ^ ((r & 7) << 4));
          bf16x8 kb = *(const bf16x8*)(Klds + byte);
          s[nt] = __builtin_amdgcn_mfma_f32_16x16x32_bf16(qa[kc], kb, s[nt], 0, 0, 0);
        }
      }

      // ---- causal mask (additive -1e9 like the reference) ----
      if (kv0 + KVB - 1 > qbase) {
        #pragma unroll
        for (int nt = 0; nt < 4; ++nt) {
          int col = kv0 + (nt << 4) + lm;
          #pragma unroll
          for (int i = 0; i < 4; ++i) {
            int row = qbase + (lg << 2) + i;
            s[nt][i] += (col > row) ? NEGBIG : 0.f;
          }
        }
      }

      // ---- online softmax: per-lane 4 rows, 16-lane group reduce ----
      float tmax[4];
      #pragma unroll
      for (int i = 0; i < 4; ++i)
        tmax[i] = fmaxf(fmaxf(s[0][i], s[1][i]), fmaxf(s[2][i], s[3][i]));
      #pragma unroll
      for (int d = 1; d < 16; d <<= 1) {
        #pragma unroll
        for (int i = 0; i < 4; ++i)
          tmax[i] = fmaxf(tmax[i], __shfl_xor(tmax[i], d));
      }
      float fac[4];
      #pragma unroll
      for (int i = 0; i < 4; ++i) {
        float mn = fmaxf(mrow[i], tmax[i]);
        fac[i] = __expf(mrow[i] - mn);
        mrow[i] = mn;
      }
      float rsum[4] = {0.f, 0.f, 0.f, 0.f};
      #pragma unroll
      for (int nt = 0; nt < 4; ++nt) {
        #pragma unroll
        for (int i = 0; i < 4; ++i) {
          float pv = __expf(s[nt][i] - mrow[i]);
          s[nt][i] = pv;
          rsum[i] += pv;
        }
      }
      #pragma unroll
      for (int d = 1; d < 16; d <<= 1) {
        #pragma unroll
        for (int i = 0; i < 4; ++i) rsum[i] += __shfl_xor(rsum[i], d);
      }
      #pragma unroll
      for (int i = 0; i < 4; ++i) lrow[i] = lrow[i] * fac[i] + rsum[i];
      #pragma unroll
      for (int nt2 = 0; nt2 < 8; ++nt2) {
        #pragma unroll
        for (int i = 0; i < 4; ++i) o[nt2][i] *= fac[i];
      }

      // ---- P: D-layout -> A-layout via per-wave swizzled LDS ----
      #pragma unroll
      for (int nt = 0; nt < 4; ++nt) {
        int colb = ((nt << 4) + lm) << 1;
        #pragma unroll
        for (int i = 0; i < 4; ++i) {
          int row = (lg << 2) + i;
          *(unsigned short*)(Plds + (row << 7) + (colb ^ ((row & 7) << 4))) =
              f2bf(s[nt][i]);
        }
      }
      asm volatile("s_waitcnt lgkmcnt(0)" ::: "memory");
      bf16x8 pa[2];
      #pragma unroll
      for (int kc = 0; kc < 2; ++kc) {
        int byte = (lm << 7) + (((kc << 6) + (lg << 4)) ^ ((lm & 7) << 4));
        pa[kc] = *(const bf16x8*)(Plds + byte);
      }

      // ---- O += P V  (V^T in LDS gives contiguous-k B-frags) ----
      #pragma unroll
      for (int nt2 = 0; nt2 < 8; ++nt2) {
        int dr = (nt2 << 4) + lm;
        #pragma unroll
        for (int kc = 0; kc < 2; ++kc) {
          int byte = (dr << 7) + (((kc << 6) + (lg << 4)) ^ ((dr & 7) << 4));
          bf16x8 vb = *(const bf16x8*)(Vlds + byte);
          o[nt2] = __builtin_amdgcn_mfma_f32_16x16x32_bf16(pa[kc], vb, o[nt2], 0, 0, 0);
        }
      }
    }
  }

  // ---- epilogue: O /= l, store f32 ----
  float inv[4];
  #pragma unroll
  for (int i = 0; i < 4; ++i) inv[i] = 1.f / lrow[i];
  #pragma unroll
  for (int nt2 = 0; nt2 < 8; ++nt2) {
    int col = h * HD + (nt2 << 4) + lm;
    #pragma unroll
    for (int i = 0; i < 4; ++i) {
      int row = qbase + (lg << 2) + i;
      out[(size_t)row * ODIM + col] = o[nt2][i] * inv[i];
    }
  }
}

extern "C" void kernel_launch(void* const* d_in, const int* in_sizes, int n_in,
                              void* d_out, int out_size, void* d_ws, size_t ws_size,
                              hipStream_t stream) {
  // inputs: [0]=input_pos(i64) [1]=q(f32) [2]=k(f32) [3]=v(f32)
  //         [4]=bsz [5]=seqlen [6]=mask(f32, pure causal -> computed analytically)
  const float* q = (const float*)d_in[1];
  const float* k = (const float*)d_in[2];
  const float* v = (const float*)d_in[3];
  float* out = (float*)d_out;
  dim3 grid(SEQ / QB / 2, NH);  // 16 balanced Q-tile pairs x 32 heads
  sdpa_flash_kernel<<<grid, 512, 0, stream>>>(q, k, v, out);
}